// Round 15
// baseline (670.747 us; speedup 1.0000x reference)
//
#include <hip/hip_runtime.h>
#include <math.h>

#define BB 2
#define SS 2048
#define DDIM 1024
#define HH 16
#define HD 64
#define MM (BB * SS)   // 4096 rows

typedef short s16x8 __attribute__((ext_vector_type(8)));
typedef short s16x4 __attribute__((ext_vector_type(4)));
typedef float f32x4 __attribute__((ext_vector_type(4)));
typedef unsigned int u32x4 __attribute__((ext_vector_type(4)));

// fp32 -> bf16 round-to-nearest-even (bit trick, finite values)
__device__ __forceinline__ unsigned short f2bf(float f) {
    unsigned int u = __builtin_bit_cast(unsigned int, f);
    u += 0x7fffu + ((u >> 16) & 1u);
    return (unsigned short)(u >> 16);
}
__device__ __forceinline__ float bf2f(unsigned short h) {
    return __builtin_bit_cast(float, (unsigned int)h << 16);
}

// ---------------------------------------------------------------------------
// wsplit: W[k][n] f32  ->  WtH/WtL [z][n][k] bf16 (transposed hi/lo split).
// 64x64 tiles via LDS. Grid (16 n-tiles, 16 k-tiles, 4 matrices).
// ---------------------------------------------------------------------------
__global__ __launch_bounds__(256) void wsplit(
    const float* __restrict__ W0, const float* __restrict__ W1,
    const float* __restrict__ W2, const float* __restrict__ W3,
    short* __restrict__ WtH, short* __restrict__ WtL)
{
    __shared__ float T[64][65];
    const int z  = blockIdx.z;
    const float* W = (z == 0) ? W0 : (z == 1) ? W1 : (z == 2) ? W2 : W3;
    const int n0 = blockIdx.x * 64;
    const int k0 = blockIdx.y * 64;
    const int t  = threadIdx.x;

#pragma unroll
    for (int i = 0; i < 4; ++i) {
        const int kr = (t >> 4) + i * 16;
        const int c4 = (t & 15) * 4;
        const float4 v = *(const float4*)&W[(size_t)(k0 + kr) * DDIM + n0 + c4];
        T[kr][c4 + 0] = v.x; T[kr][c4 + 1] = v.y;
        T[kr][c4 + 2] = v.z; T[kr][c4 + 3] = v.w;
    }
    __syncthreads();

    const int n  = t >> 2;
    const int kb = (t & 3) * 16;
    s16x8 h0, h1, l0, l1;
#pragma unroll
    for (int j = 0; j < 8; ++j) {
        const float f0 = T[kb + j][n];
        const unsigned short hh0 = f2bf(f0);
        h0[j] = (short)hh0; l0[j] = (short)f2bf(f0 - bf2f(hh0));
        const float f1 = T[kb + 8 + j][n];
        const unsigned short hh1 = f2bf(f1);
        h1[j] = (short)hh1; l1[j] = (short)f2bf(f1 - bf2f(hh1));
    }
    const size_t ob = ((size_t)z * DDIM + n0 + n) * DDIM + k0 + kb;
    *(s16x8*)&WtH[ob]     = h0;
    *(s16x8*)&WtH[ob + 8] = h1;
    *(s16x8*)&WtL[ob]     = l0;
    *(s16x8*)&WtL[ob + 8] = l1;
}

// ---------------------------------------------------------------------------
// asplit: X[n] f32 -> XH/XL bf16 hi/lo, elementwise (8 per thread).
// Used on x (before Q/K/V proj) and on Ab (before output proj).
// ---------------------------------------------------------------------------
__global__ __launch_bounds__(256) void asplit(
    const float* __restrict__ X, short* __restrict__ XH, short* __restrict__ XL)
{
    const size_t i = ((size_t)blockIdx.x * 256 + threadIdx.x) * 8;
    const float4 v0 = *(const float4*)&X[i];
    const float4 v1 = *(const float4*)&X[i + 4];
    const float f[8] = {v0.x, v0.y, v0.z, v0.w, v1.x, v1.y, v1.z, v1.w};
    s16x8 h, l;
#pragma unroll
    for (int j = 0; j < 8; ++j) {
        const unsigned short hh = f2bf(f[j]);
        h[j] = (short)hh;
        l[j] = (short)f2bf(f[j] - bf2f(hh));
    }
    *(s16x8*)&XH[i] = h;
    *(s16x8*)&XL[i] = l;
}

// ---------------------------------------------------------------------------
// proj_v3: C = A(split bf16) @ B(split bf16, [n][k]) + bias.
// 3-pass split accumulation (AhBh + AhBl + AlBh).  NO LDS, NO barriers:
// A/B tiles are L2/L3-resident; K-loop is pure global-load + MFMA.
// Tile 64x64, 4 waves (2x2), wave-tile 32x32. Grid 16x64 -> 4 blocks/CU.
// MODE 0: Q' [B,H,S,128] bf16 hi|lo   MODE 1: K [B,H,S,64] bf16
// MODE 2: V^T [B,H,64,S] bf16         MODE 3: out [M,1024] f32
// ---------------------------------------------------------------------------
template <int MODE>
__global__ __launch_bounds__(256) void proj_v3(
    const short* __restrict__ AH, const short* __restrict__ AL,
    const short* __restrict__ BTh, const short* __restrict__ BTl,
    const float* __restrict__ bias, void* __restrict__ Cout)
{
    const int tid  = threadIdx.x;
    const int lane = tid & 63;
    const int wave = tid >> 6;
    const int g    = lane >> 4;
    const int qq   = lane & 15;
    const int wm   = (wave >> 1) * 32;
    const int wn   = (wave & 1) * 32;
    const int n0   = blockIdx.x * 64;
    const int m0   = blockIdx.y * 64;

    const size_t ar0 = (size_t)(m0 + wm + qq) * DDIM;
    const size_t ar1 = (size_t)(m0 + wm + 16 + qq) * DDIM;
    const size_t br0 = (size_t)(n0 + wn + qq) * DDIM;
    const size_t br1 = (size_t)(n0 + wn + 16 + qq) * DDIM;

    f32x4 acc[2][2];
#pragma unroll
    for (int i = 0; i < 2; ++i)
#pragma unroll
        for (int j = 0; j < 2; ++j) acc[i][j] = (f32x4){0.f, 0.f, 0.f, 0.f};

#pragma unroll 2
    for (int k0 = 0; k0 < DDIM; k0 += 32) {
        const int kc = k0 + g * 8;
        const s16x8 ah0 = *(const s16x8*)&AH[ar0 + kc];
        const s16x8 al0 = *(const s16x8*)&AL[ar0 + kc];
        const s16x8 ah1 = *(const s16x8*)&AH[ar1 + kc];
        const s16x8 al1 = *(const s16x8*)&AL[ar1 + kc];
        const s16x8 bh0 = *(const s16x8*)&BTh[br0 + kc];
        const s16x8 bl0 = *(const s16x8*)&BTl[br0 + kc];
        const s16x8 bh1 = *(const s16x8*)&BTh[br1 + kc];
        const s16x8 bl1 = *(const s16x8*)&BTl[br1 + kc];

        acc[0][0] = __builtin_amdgcn_mfma_f32_16x16x32_bf16(ah0, bh0, acc[0][0], 0, 0, 0);
        acc[0][1] = __builtin_amdgcn_mfma_f32_16x16x32_bf16(ah0, bh1, acc[0][1], 0, 0, 0);
        acc[1][0] = __builtin_amdgcn_mfma_f32_16x16x32_bf16(ah1, bh0, acc[1][0], 0, 0, 0);
        acc[1][1] = __builtin_amdgcn_mfma_f32_16x16x32_bf16(ah1, bh1, acc[1][1], 0, 0, 0);
        acc[0][0] = __builtin_amdgcn_mfma_f32_16x16x32_bf16(ah0, bl0, acc[0][0], 0, 0, 0);
        acc[0][1] = __builtin_amdgcn_mfma_f32_16x16x32_bf16(ah0, bl1, acc[0][1], 0, 0, 0);
        acc[1][0] = __builtin_amdgcn_mfma_f32_16x16x32_bf16(ah1, bl0, acc[1][0], 0, 0, 0);
        acc[1][1] = __builtin_amdgcn_mfma_f32_16x16x32_bf16(ah1, bl1, acc[1][1], 0, 0, 0);
        acc[0][0] = __builtin_amdgcn_mfma_f32_16x16x32_bf16(al0, bh0, acc[0][0], 0, 0, 0);
        acc[0][1] = __builtin_amdgcn_mfma_f32_16x16x32_bf16(al0, bh1, acc[0][1], 0, 0, 0);
        acc[1][0] = __builtin_amdgcn_mfma_f32_16x16x32_bf16(al1, bh0, acc[1][0], 0, 0, 0);
        acc[1][1] = __builtin_amdgcn_mfma_f32_16x16x32_bf16(al1, bh1, acc[1][1], 0, 0, 0);
    }

    // ---- epilogue ----
    float bv2[2];
#pragma unroll
    for (int nf = 0; nf < 2; ++nf) bv2[nf] = bias[n0 + wn + 16 * nf + qq];

#pragma unroll
    for (int mf = 0; mf < 2; ++mf) {
#pragma unroll
        for (int nf = 0; nf < 2; ++nf) {
            const int ncol = n0 + wn + 16 * nf + qq;
            if (MODE == 2) {
                const int mbase = m0 + wm + 16 * mf + 4 * g;
                const int b = mbase >> 11, s = mbase & 2047;
                const int h = ncol >> 6, d = ncol & 63;
                short p4[4];
#pragma unroll
                for (int r = 0; r < 4; ++r)
                    p4[r] = (short)f2bf(acc[mf][nf][r] + bv2[nf]);
                const s16x4 pv = {p4[0], p4[1], p4[2], p4[3]};
                *(s16x4*)&((short*)Cout)[(((size_t)(b * HH + h)) * HD + d) * SS + s] = pv;
            } else {
#pragma unroll
                for (int r = 0; r < 4; ++r) {
                    const int mrow = m0 + wm + 16 * mf + 4 * g + r;
                    const float val = acc[mf][nf][r] + bv2[nf];
                    if (MODE == 3) {
                        ((float*)Cout)[(size_t)mrow * DDIM + ncol] = val;
                    } else {
                        const int b = mrow >> 11, s = mrow & 2047;
                        const int h = ncol >> 6, d = ncol & 63;
                        if (MODE == 0) {
                            short* Q = (short*)Cout;
                            const size_t base = (((size_t)(b * HH + h)) * SS + s) * 128;
                            const unsigned short hh = f2bf(val);
                            Q[base + d]      = (short)hh;
                            Q[base + 64 + d] = (short)f2bf(val - bf2f(hh));
                        } else { // MODE 1: K
                            ((short*)Cout)[(((size_t)(b * HH + h)) * SS + s) * 64 + d] = (short)f2bf(val);
                        }
                    }
                }
            }
        }
    }
}

// ---------------------------------------------------------------------------
// Flash attention, bf16 MFMA (UNCHANGED from passing R9 kernel).
// ---------------------------------------------------------------------------
__global__ __launch_bounds__(256) void attn_mfma(
    const short* __restrict__ Qp, const short* __restrict__ Kp,
    const short* __restrict__ Vt, float* __restrict__ Ab)
{
    __shared__ short Kt[64 * 64];
    __shared__ short Vs[64 * 64];

    const int tid  = threadIdx.x;
    const int lane = tid & 63;
    const int wave = tid >> 6;
    const int g    = lane >> 4;
    const int qq   = lane & 15;
    const int qt   = 31 - blockIdx.x;      // heavy (long-k) blocks first
    const int h    = blockIdx.y;
    const int b    = blockIdx.z;
    const int q0   = qt * 64;
    const int qrow = q0 + wave * 16 + qq;

    const size_t headoff = (size_t)(b * HH + h) * SS;

    s16x8 qf[2][2];
#pragma unroll
    for (int half = 0; half < 2; ++half)
#pragma unroll
        for (int ks2 = 0; ks2 < 2; ++ks2)
            qf[half][ks2] = *(const s16x8*)&Qp[(headoff + qrow) * 128 + half * 64 + ks2 * 32 + g * 8];

    f32x4 oacc[4];
#pragma unroll
    for (int i = 0; i < 4; ++i) oacc[i] = (f32x4){0.f, 0.f, 0.f, 0.f};
    float mrun = -INFINITY, lrun = 0.f;

    for (int kt = 0; kt <= qt; ++kt) {
        const int kc0 = kt * 64;
        __syncthreads();
#pragma unroll
        for (int uu = 0; uu < 2; ++uu) {
            const int S = uu * 256 + tid;
            const int row = S >> 3, sl = S & 7;
            const int dsl = (sl ^ (row & 7)) * 8;
            const s16x8 kv = *(const s16x8*)&Kp[(headoff + kc0 + row) * 64 + sl * 8];
            *(s16x8*)&Kt[row * 64 + dsl] = kv;
            const s16x8 vv = *(const s16x8*)&Vt[((size_t)(b * HH + h) * HD + row) * SS + kc0 + sl * 8];
            *(s16x8*)&Vs[row * 64 + dsl] = vv;
        }
        __syncthreads();

        f32x4 sacc[4];
#pragma unroll
        for (int i = 0; i < 4; ++i) sacc[i] = (f32x4){0.f, 0.f, 0.f, 0.f};
#pragma unroll
        for (int kcf = 0; kcf < 4; ++kcf) {
            const int row = kcf * 16 + qq;
            s16x8 kf[2];
#pragma unroll
            for (int ks2 = 0; ks2 < 2; ++ks2)
                kf[ks2] = *(const s16x8*)&Kt[row * 64 + (((ks2 * 4 + g) ^ (row & 7)) * 8)];
#pragma unroll
            for (int half = 0; half < 2; ++half)
#pragma unroll
                for (int ks2 = 0; ks2 < 2; ++ks2)
                    sacc[kcf] = __builtin_amdgcn_mfma_f32_16x16x32_bf16(kf[ks2], qf[half][ks2], sacc[kcf], 0, 0, 0);
        }

        float sc[16];
        float pmax = -INFINITY;
#pragma unroll
        for (int kcf = 0; kcf < 4; ++kcf)
#pragma unroll
            for (int r = 0; r < 4; ++r) {
                float v = sacc[kcf][r] * 0.125f;
                const int kc = kc0 + kcf * 16 + g * 4 + r;
                if (kc > qrow) v = -INFINITY;
                sc[kcf * 4 + r] = v;
                pmax = fmaxf(pmax, v);
            }
        pmax = fmaxf(pmax, __shfl_xor(pmax, 16));
        pmax = fmaxf(pmax, __shfl_xor(pmax, 32));
        const float mnew  = fmaxf(mrun, pmax);
        const float alpha = __expf(mrun - mnew);
        float p[16], psum = 0.f;
#pragma unroll
        for (int i = 0; i < 16; ++i) { p[i] = __expf(sc[i] - mnew); psum += p[i]; }
        psum += __shfl_xor(psum, 16);
        psum += __shfl_xor(psum, 32);
        lrun = lrun * alpha + psum;
        mrun = mnew;
#pragma unroll
        for (int df = 0; df < 4; ++df) oacc[df] *= alpha;

        unsigned int pk[4][2];
#pragma unroll
        for (int kcf = 0; kcf < 4; ++kcf)
#pragma unroll
            for (int hh = 0; hh < 2; ++hh)
                pk[kcf][hh] = (unsigned int)f2bf(p[kcf * 4 + 2 * hh]) |
                              ((unsigned int)f2bf(p[kcf * 4 + 2 * hh + 1]) << 16);

        s16x8 pb[2];
#pragma unroll
        for (int ks = 0; ks < 2; ++ks) {
            unsigned int w_[4];
#pragma unroll
            for (int w = 0; w < 2 * 2; ++w) {
                const int gs  = (2 * g + (w >> 1)) & 3;
                const int src = qq | (gs << 4);
                const unsigned int va = (unsigned int)__shfl((int)pk[2 * ks][w & 1], src);
                const unsigned int vb = (unsigned int)__shfl((int)pk[2 * ks + 1][w & 1], src);
                w_[w] = (g & 2) ? vb : va;
            }
            const u32x4 t = {w_[0], w_[1], w_[2], w_[3]};
            pb[ks] = __builtin_bit_cast(s16x8, t);
        }

#pragma unroll
        for (int df = 0; df < 4; ++df) {
            const int row = df * 16 + qq;
#pragma unroll
            for (int ks = 0; ks < 2; ++ks) {
                const s16x8 vf = *(const s16x8*)&Vs[row * 64 + (((ks * 4 + g) ^ (row & 7)) * 8)];
                oacc[df] = __builtin_amdgcn_mfma_f32_16x16x32_bf16(vf, pb[ks], oacc[df], 0, 0, 0);
            }
        }
    }

    const float inv = 1.0f / lrun;
#pragma unroll
    for (int df = 0; df < 4; ++df) {
        f32x4 r = oacc[df];
        r *= inv;
        *(f32x4*)&Ab[((size_t)b * SS + qrow) * DDIM + h * HD + df * 16 + g * 4] = r;
    }
}

// ---------------------------------------------------------------------------
extern "C" void kernel_launch(void* const* d_in, const int* in_sizes, int n_in,
                              void* d_out, int out_size, void* d_ws, size_t ws_size,
                              hipStream_t stream)
{
    const float* x  = (const float*)d_in[0];
    const float* Wq = (const float*)d_in[2];
    const float* bq = (const float*)d_in[3];
    const float* Wk = (const float*)d_in[4];
    const float* bk = (const float*)d_in[5];
    const float* Wv = (const float*)d_in[6];
    const float* bv = (const float*)d_in[7];
    const float* Wo = (const float*)d_in[8];
    const float* bo = (const float*)d_in[9];
    float* out = (float*)d_out;

    // d_ws: 64 MiB total (R1 proved 64 MiB works).  Qp lives in d_out.
    char* w = (char*)d_ws;
    short* Kp  = (short*)w;                               //  8 MiB [B,H,S,64]
    short* Vt  = (short*)(w + (size_t) 8 * 1024 * 1024);  //  8 MiB [B,H,64,S]
    float* Ab  = (float*)(w + (size_t)16 * 1024 * 1024);  // 16 MiB [M,1024] f32
    short* WtH = (short*)(w + (size_t)32 * 1024 * 1024);  //  8 MiB [4][n][k]
    short* WtL = (short*)(w + (size_t)40 * 1024 * 1024);  //  8 MiB [4][n][k]
    short* AH  = (short*)(w + (size_t)48 * 1024 * 1024);  //  8 MiB [M][1024]
    short* AL  = (short*)(w + (size_t)56 * 1024 * 1024);  //  8 MiB [M][1024]
    short* Qp  = (short*)d_out;                           // 16 MiB [B,H,S,128]

    const dim3 blk(256);
    const dim3 gg(DDIM / 64, MM / 64);       // 16 x 64 = 1024 blocks
    const int  asplit_blocks = MM * DDIM / (256 * 8);   // 2048

    wsplit<<<dim3(16, 16, 4), blk, 0, stream>>>(Wq, Wk, Wv, Wo, WtH, WtL);
    asplit<<<asplit_blocks, blk, 0, stream>>>(x, AH, AL);

    proj_v3<0><<<gg, blk, 0, stream>>>(AH, AL, WtH + (size_t)0 * 1048576, WtL + (size_t)0 * 1048576, bq, (void*)Qp);
    proj_v3<1><<<gg, blk, 0, stream>>>(AH, AL, WtH + (size_t)1 * 1048576, WtL + (size_t)1 * 1048576, bk, (void*)Kp);
    proj_v3<2><<<gg, blk, 0, stream>>>(AH, AL, WtH + (size_t)2 * 1048576, WtL + (size_t)2 * 1048576, bv, (void*)Vt);

    attn_mfma<<<dim3(32, HH, BB), blk, 0, stream>>>(Qp, Kp, Vt, Ab);

    asplit<<<asplit_blocks, blk, 0, stream>>>(Ab, AH, AL);
    proj_v3<3><<<gg, blk, 0, stream>>>(AH, AL, WtH + (size_t)3 * 1048576, WtL + (size_t)3 * 1048576, bo, (void*)out);
}